// Round 1
// baseline (697.379 us; speedup 1.0000x reference)
//
#include <hip/hip_runtime.h>
#include <stdint.h>
#include <stddef.h>

#define Bb 16
#define Ss 64
#define Hh 4096
#define NKVv 8
#define HDd 128
#define LCACHE 4608
#define MM (Bb*Ss)            // 1024
#define NQKV (Hh + 2*NKVv*HDd) // 6144
#define SCALE_Q 0.08838834764831845f

typedef float fx4 __attribute__((ext_vector_type(4)));
typedef short s16x8 __attribute__((ext_vector_type(8)));
typedef unsigned short u16;
typedef unsigned short u16x8 __attribute__((ext_vector_type(8)));
typedef unsigned short u16x4 __attribute__((ext_vector_type(4)));

__device__ __forceinline__ u16 f2bf(float f) {
  union { float f; unsigned u; } x; x.f = f;
  unsigned r = x.u + 0x7FFFu + ((x.u >> 16) & 1u);
  return (u16)(r >> 16);
}

__device__ __forceinline__ fx4 MFMA(s16x8 a, s16x8 b, fx4 c) {
  return __builtin_amdgcn_mfma_f32_16x16x32_bf16(a, b, c, 0, 0, 0);
}

// ---------------- cast f32 -> bf16 (8 elems/thread) ----------------
__global__ __launch_bounds__(256) void cast_bf16_kernel(
    const float* __restrict__ src, u16* __restrict__ dst, int n8) {
  int i = blockIdx.x * 256 + threadIdx.x;
  if (i >= n8) return;
  fx4 a = *(const fx4*)(src + (size_t)i * 8);
  fx4 b = *(const fx4*)(src + (size_t)i * 8 + 4);
  u16x8 o;
  o[0]=f2bf(a[0]); o[1]=f2bf(a[1]); o[2]=f2bf(a[2]); o[3]=f2bf(a[3]);
  o[4]=f2bf(b[0]); o[5]=f2bf(b[1]); o[6]=f2bf(b[2]); o[7]=f2bf(b[3]);
  *(u16x8*)(dst + (size_t)i * 8) = o;
}

// ---------------- BT-GEMM: C[m,n] = sum_k A[m,k]*W[n,k] + bias[n] ----------------
// 128x128 tile, BK=32, 4 waves (2x2), each wave 64x64 via 4x4 16x16x32 MFMA frags.
__global__ __launch_bounds__(256) void gemm_bt_kernel(
    const u16* __restrict__ A, const u16* __restrict__ W,
    const float* __restrict__ bias, float* __restrict__ C,
    int M, int N, int K)
{
  __shared__ __align__(16) u16 As[128*32];
  __shared__ __align__(16) u16 Ws[128*32];
  const int t = threadIdx.x;
  const int lane = t & 63, w = t >> 6;
  const int wr = (w >> 1) * 64, wc = (w & 1) * 64;
  const int lr = lane & 15, lg = lane >> 4;
  const int mt = blockIdx.y * 128, nt = blockIdx.x * 128;

  fx4 acc[4][4];
#pragma unroll
  for (int i = 0; i < 4; i++)
#pragma unroll
    for (int j = 0; j < 4; j++) acc[i][j] = (fx4){0.f,0.f,0.f,0.f};

  const int srow = t >> 2, scol = (t & 3) * 8;
  const u16* Ag0 = A + (size_t)(mt + srow) * K + scol;
  const u16* Ag1 = A + (size_t)(mt + 64 + srow) * K + scol;
  const u16* Wg0 = W + (size_t)(nt + srow) * K + scol;
  const u16* Wg1 = W + (size_t)(nt + 64 + srow) * K + scol;
  u16* As0 = As + srow*32 + scol;
  u16* As1 = As + (64+srow)*32 + scol;
  u16* Ws0 = Ws + srow*32 + scol;
  u16* Ws1 = Ws + (64+srow)*32 + scol;

  for (int k0 = 0; k0 < K; k0 += 32) {
    __syncthreads();
    *(u16x8*)As0 = *(const u16x8*)(Ag0 + k0);
    *(u16x8*)As1 = *(const u16x8*)(Ag1 + k0);
    *(u16x8*)Ws0 = *(const u16x8*)(Wg0 + k0);
    *(u16x8*)Ws1 = *(const u16x8*)(Wg1 + k0);
    __syncthreads();
    s16x8 af[4], bfr[4];
#pragma unroll
    for (int i = 0; i < 4; i++)
      af[i] = *(const s16x8*)(As + (wr + i*16 + lr)*32 + lg*8);
#pragma unroll
    for (int j = 0; j < 4; j++)
      bfr[j] = *(const s16x8*)(Ws + (wc + j*16 + lr)*32 + lg*8);
#pragma unroll
    for (int i = 0; i < 4; i++)
#pragma unroll
      for (int j = 0; j < 4; j++)
        acc[i][j] = MFMA(af[i], bfr[j], acc[i][j]);
  }

#pragma unroll
  for (int j = 0; j < 4; j++) {
    const int col = nt + wc + j*16 + lr;
    const float bv = bias ? bias[col] : 0.0f;
#pragma unroll
    for (int i = 0; i < 4; i++) {
      const int row0 = mt + wr + i*16 + lg*4;
#pragma unroll
      for (int q = 0; q < 4; q++)
        C[(size_t)(row0 + q) * N + col] = acc[i][j][q] + bv;
    }
  }
}

// ---------------- RoPE + repack to bf16 ----------------
// qkv: [1024][6144] f32. One wave per (token m, head-task).
// tasks: 0..31 q heads (scale folded), 32..39 k heads, 40..47 v heads (cast only).
__global__ __launch_bounds__(256) void rope_split_kernel(
    const float* __restrict__ qkv, const float* __restrict__ cosb,
    const float* __restrict__ sinb, u16* __restrict__ qb,
    u16* __restrict__ kb, u16* __restrict__ vb)
{
  const int wt = blockIdx.x * 4 + (threadIdx.x >> 6);
  const int lane = threadIdx.x & 63;
  const int m = wt / 48;
  const int task = wt - m * 48;
  const int b = m >> 6, s = m & 63;
  const float* row = qkv + (size_t)m * NQKV;

  if (task < 32) {
    const int h = task;
    const float x1 = row[h*128 + lane];
    const float x2 = row[h*128 + 64 + lane];
    const float c = cosb[m*128 + lane];
    const float sn = sinb[m*128 + lane];
    u16* dst = qb + (((size_t)(b*8 + (h>>2)))*256 + (h&3)*64 + s) * 128;
    dst[lane]      = f2bf((x1*c - x2*sn) * SCALE_Q);
    dst[lane + 64] = f2bf((x2*c + x1*sn) * SCALE_Q);
  } else if (task < 40) {
    const int n = task - 32;
    const float x1 = row[4096 + n*128 + lane];
    const float x2 = row[4096 + n*128 + 64 + lane];
    const float c = cosb[m*128 + lane];
    const float sn = sinb[m*128 + lane];
    u16* dst = kb + (((size_t)(b*8 + n))*64 + s) * 128;
    dst[lane]      = f2bf(x1*c - x2*sn);
    dst[lane + 64] = f2bf(x2*c + x1*sn);
  } else {
    const int n = task - 40;
    const float x1 = row[5120 + n*128 + lane];
    const float x2 = row[5120 + n*128 + 64 + lane];
    u16* dst = vb + (((size_t)(b*8 + n))*64 + s) * 128;
    dst[lane]      = f2bf(x1);
    dst[lane + 64] = f2bf(x2);
  }
}

// ---------------- fused flash attention (prefix cache + causal current tile) ----------------
// block = (b, kv-head n). 512 threads = 8 waves, each wave owns 32 query rows
// (rows r = g*64+s; wave w -> g=w>>1, s in (w&1)*32..+31).
__global__ __launch_bounds__(512) void flash_kernel(
    const u16* __restrict__ qb, const u16* __restrict__ kb, const u16* __restrict__ vb,
    const float* __restrict__ kc, const float* __restrict__ vc,
    const int* __restrict__ cache_lens, u16* __restrict__ attn)
{
  __shared__ __align__(16) u16 Kt[64*128];   // [t][d], byte ^ ((t&7)<<4)
  __shared__ __align__(16) u16 Vt[128*64];   // [d][t], byte ^ ((d&7)<<4)
  __shared__ __align__(16) u16 Pl[8*32*64];  // per-wave P, byte ^ (((row>>2)&3)<<5)

  const int bn = blockIdx.x;
  const int b = bn >> 3, n = bn & 7;
  const int t = threadIdx.x;
  const int lane = t & 63, w = t >> 6;
  const int lr = lane & 15, lg = lane >> 4;
  const int L = cache_lens[b];

  s16x8 qf[2][4];
  const u16* qbase = qb + ((size_t)bn*256 + w*32) * 128;
#pragma unroll
  for (int rf = 0; rf < 2; rf++)
#pragma unroll
    for (int ks = 0; ks < 4; ks++)
      qf[rf][ks] = *(const s16x8*)(qbase + (rf*16 + lr)*128 + ks*32 + lg*8);

  fx4 O[2][8];
  float m_r[2][4], l_r[2][4];
#pragma unroll
  for (int rf = 0; rf < 2; rf++) {
#pragma unroll
    for (int cn = 0; cn < 8; cn++) O[rf][cn] = (fx4){0.f,0.f,0.f,0.f};
#pragma unroll
    for (int i = 0; i < 4; i++) { m_r[rf][i] = -1e30f; l_r[rf][i] = 0.f; }
  }

  const int ntile = (L + 63) >> 6;
  const int krow = t >> 3, kcol = (t & 7) * 16;   // K staging: 64 rows x 16 cols/thread
  const int vd0 = (t >> 4) * 4, vr0 = (t & 15) * 4; // V staging: 4 d x 4 r per thread
  char* pw = (char*)Pl + w * 4096;

  for (int tile = 0; tile <= ntile; ++tile) {
    const int l0 = tile * 64;
    const bool cur = (tile == ntile);
    __syncthreads();
    if (!cur) {
      { // K tile f32 -> bf16, row-major [t][d]
        const float* src = kc + (((size_t)b*LCACHE + l0 + krow)*NKVv + n)*HDd + kcol;
        const bool valid = (l0 + krow) < L;
#pragma unroll
        for (int jj = 0; jj < 2; jj++) {
          u16x8 v8 = {0,0,0,0,0,0,0,0};
          if (valid) {
            fx4 f0 = *(const fx4*)(src + jj*8);
            fx4 f1 = *(const fx4*)(src + jj*8 + 4);
            v8[0]=f2bf(f0[0]); v8[1]=f2bf(f0[1]); v8[2]=f2bf(f0[2]); v8[3]=f2bf(f0[3]);
            v8[4]=f2bf(f1[0]); v8[5]=f2bf(f1[1]); v8[6]=f2bf(f1[2]); v8[7]=f2bf(f1[3]);
          }
          const int byt = (krow*256 + (kcol + jj*8)*2) ^ ((krow & 7) << 4);
          *(u16x8*)((char*)Kt + byt) = v8;
        }
      }
      { // V tile transposed [d][t]
        const float* srcv = vc + (((size_t)b*LCACHE + l0 + vr0)*NKVv + n)*HDd + vd0;
        fx4 vv[4];
        const fx4 z = {0.f,0.f,0.f,0.f};
#pragma unroll
        for (int j = 0; j < 4; j++) {
          const bool valid = (l0 + vr0 + j) < L;
          vv[j] = valid ? *(const fx4*)(srcv + (size_t)j*(NKVv*HDd)) : z;
        }
#pragma unroll
        for (int dd = 0; dd < 4; dd++) {
          u16x4 pk;
          pk[0]=f2bf(vv[0][dd]); pk[1]=f2bf(vv[1][dd]); pk[2]=f2bf(vv[2][dd]); pk[3]=f2bf(vv[3][dd]);
          const int d = vd0 + dd;
          const int byt = (d*128 + vr0*2) ^ ((d & 7) << 4);
          *(u16x4*)((char*)Vt + byt) = pk;
        }
      }
    } else {
      { // current K tile from kb (bf16 already)
        const u16* src = kb + ((size_t)bn*64 + krow)*128 + kcol;
#pragma unroll
        for (int jj = 0; jj < 2; jj++) {
          u16x8 v8 = *(const u16x8*)(src + jj*8);
          const int byt = (krow*256 + (kcol + jj*8)*2) ^ ((krow & 7) << 4);
          *(u16x8*)((char*)Kt + byt) = v8;
        }
      }
      { // current V tile transposed
        const u16* srcv = vb + (size_t)bn*64*128 + (size_t)vr0*128 + vd0;
        u16x4 vv[4];
#pragma unroll
        for (int j = 0; j < 4; j++) vv[j] = *(const u16x4*)(srcv + j*128);
#pragma unroll
        for (int dd = 0; dd < 4; dd++) {
          u16x4 pk; pk[0]=vv[0][dd]; pk[1]=vv[1][dd]; pk[2]=vv[2][dd]; pk[3]=vv[3][dd];
          const int d = vd0 + dd;
          const int byt = (d*128 + vr0*2) ^ ((d & 7) << 4);
          *(u16x4*)((char*)Vt + byt) = pk;
        }
      }
    }
    __syncthreads();

    // QK^T: sc rows = query rows (D layout), cols = kv pos in tile
    fx4 sc[2][4];
#pragma unroll
    for (int cf = 0; cf < 4; cf++) {
      s16x8 kf[4];
      const int trow = cf*16 + lr;
#pragma unroll
      for (int ks = 0; ks < 4; ks++) {
        const int byt = (trow*256 + (ks*32 + lg*8)*2) ^ ((trow & 7) << 4);
        kf[ks] = *(const s16x8*)((char*)Kt + byt);
      }
#pragma unroll
      for (int rf = 0; rf < 2; rf++) {
        fx4 s = {0.f,0.f,0.f,0.f};
#pragma unroll
        for (int ks = 0; ks < 4; ks++) s = MFMA(qf[rf][ks], kf[ks], s);
        sc[rf][cf] = s;
      }
    }

    // masking
    if (cur) {
#pragma unroll
      for (int rf = 0; rf < 2; rf++)
#pragma unroll
        for (int cf = 0; cf < 4; cf++) {
          const int col = cf*16 + lr;
#pragma unroll
          for (int i = 0; i < 4; i++) {
            const int sq = (w & 1)*32 + rf*16 + lg*4 + i;
            if (col > sq) sc[rf][cf][i] = -1e30f;
          }
        }
    } else if (l0 + 64 > L) {
#pragma unroll
      for (int cf = 0; cf < 4; cf++) {
        const int tp = l0 + cf*16 + lr;
        if (tp >= L) {
#pragma unroll
          for (int rf = 0; rf < 2; rf++)
#pragma unroll
            for (int i = 0; i < 4; i++) sc[rf][cf][i] = -1e30f;
        }
      }
    }

    // online softmax + write P (bf16) to per-wave LDS
#pragma unroll
    for (int rf = 0; rf < 2; rf++) {
#pragma unroll
      for (int i = 0; i < 4; i++) {
        float v = fmaxf(fmaxf(sc[rf][0][i], sc[rf][1][i]), fmaxf(sc[rf][2][i], sc[rf][3][i]));
        v = fmaxf(v, __shfl_xor(v, 1));
        v = fmaxf(v, __shfl_xor(v, 2));
        v = fmaxf(v, __shfl_xor(v, 4));
        v = fmaxf(v, __shfl_xor(v, 8));
        const float nm = fmaxf(m_r[rf][i], v);
        const float sf = __expf(m_r[rf][i] - nm);
        m_r[rf][i] = nm;
        float rs = 0.f;
#pragma unroll
        for (int cf = 0; cf < 4; cf++) {
          const float p = __expf(sc[rf][cf][i] - nm);
          sc[rf][cf][i] = p;
          rs += p;
        }
        rs += __shfl_xor(rs, 1);
        rs += __shfl_xor(rs, 2);
        rs += __shfl_xor(rs, 4);
        rs += __shfl_xor(rs, 8);
        l_r[rf][i] = l_r[rf][i]*sf + rs;
#pragma unroll
        for (int cn = 0; cn < 8; cn++) O[rf][cn][i] *= sf;
      }
#pragma unroll
      for (int cf = 0; cf < 4; cf++)
#pragma unroll
        for (int i = 0; i < 4; i++) {
          const int prow = rf*16 + lg*4 + i;
          const int pcol = cf*16 + lr;
          const int byt = (prow*128 + pcol*2) ^ (((prow >> 2) & 3) << 5);
          *(u16*)(pw + byt) = f2bf(sc[rf][cf][i]);
        }
    }

    // PV: O += P @ V
#pragma unroll
    for (int ks = 0; ks < 2; ks++) {
      s16x8 vf[8];
#pragma unroll
      for (int cn = 0; cn < 8; cn++) {
        const int c = cn*16 + lr;
        const int byt = (c*128 + (ks*32 + lg*8)*2) ^ ((c & 7) << 4);
        vf[cn] = *(const s16x8*)((char*)Vt + byt);
      }
#pragma unroll
      for (int rf = 0; rf < 2; rf++) {
        const int prow = rf*16 + lr;
        const int byt = (prow*128 + (ks*32 + lg*8)*2) ^ (((prow >> 2) & 3) << 5);
        const s16x8 pf = *(const s16x8*)(pw + byt);
#pragma unroll
        for (int cn = 0; cn < 8; cn++)
          O[rf][cn] = MFMA(pf, vf[cn], O[rf][cn]);
      }
    }
  }

  // normalize + store bf16 attn [1024][4096]
  const int head = n*4 + (w >> 1);
#pragma unroll
  for (int rf = 0; rf < 2; rf++)
#pragma unroll
    for (int i = 0; i < 4; i++) {
      const int s = (w & 1)*32 + rf*16 + lg*4 + i;
      const float inv = 1.f / l_r[rf][i];
      u16* dst = attn + ((size_t)(b*64 + s))*4096 + (size_t)head*128;
#pragma unroll
      for (int cn = 0; cn < 8; cn++)
        dst[cn*16 + lr] = f2bf(O[rf][cn][i] * inv);
    }
}

// ---------------- launch ----------------
extern "C" void kernel_launch(void* const* d_in, const int* in_sizes, int n_in,
                              void* d_out, int out_size, void* d_ws, size_t ws_size,
                              hipStream_t stream) {
  (void)in_sizes; (void)n_in; (void)out_size; (void)ws_size;
  const float* hidden = (const float*)d_in[0];
  const float* cosb   = (const float*)d_in[1];
  const float* sinb   = (const float*)d_in[2];
  const float* kc     = (const float*)d_in[3];
  const float* vc     = (const float*)d_in[4];
  const float* wq     = (const float*)d_in[5];
  const float* bq     = (const float*)d_in[6];
  const float* wk     = (const float*)d_in[7];
  const float* bk     = (const float*)d_in[8];
  const float* wv     = (const float*)d_in[9];
  const float* bv     = (const float*)d_in[10];
  const float* wo     = (const float*)d_in[11];
  const int* clens    = (const int*)d_in[12];
  float* out = (float*)d_out;

  char* ws = (char*)d_ws;
  size_t off = 0;
  auto alloc = [&](size_t bytes) -> void* {
    void* p = ws + off; off += (bytes + 255) & ~(size_t)255; return p;
  };
  u16* Wqkv  = (u16*)alloc((size_t)NQKV * Hh * 2);          // 50.3 MB (reused for wo)
  u16* Xb    = (u16*)alloc((size_t)MM * Hh * 2);            // 8 MB (reused for attn)
  float* qkvf= (float*)alloc((size_t)MM * NQKV * 4);        // 24 MB
  u16* qbuf  = (u16*)alloc((size_t)Bb*NKVv*256*HDd*2);      // 8 MB
  u16* kbuf  = (u16*)alloc((size_t)Bb*NKVv*64*HDd*2);       // 2 MB
  u16* vbuf  = (u16*)alloc((size_t)Bb*NKVv*64*HDd*2);       // 2 MB
  float* biasq = (float*)alloc((size_t)NQKV * 4);

  hipMemcpyAsync(biasq,        bq, 4096*sizeof(float), hipMemcpyDeviceToDevice, stream);
  hipMemcpyAsync(biasq + 4096, bk, 1024*sizeof(float), hipMemcpyDeviceToDevice, stream);
  hipMemcpyAsync(biasq + 5120, bv, 1024*sizeof(float), hipMemcpyDeviceToDevice, stream);

  auto cast = [&](const float* s, u16* d, size_t nelem) {
    int n8 = (int)(nelem / 8);
    cast_bf16_kernel<<<(n8 + 255) / 256, 256, 0, stream>>>(s, d, n8);
  };
  cast(hidden, Xb, (size_t)MM * Hh);
  cast(wq, Wqkv,                      (size_t)4096 * 4096);
  cast(wk, Wqkv + (size_t)4096*4096,  (size_t)1024 * 4096);
  cast(wv, Wqkv + (size_t)5120*4096,  (size_t)1024 * 4096);

  gemm_bt_kernel<<<dim3(NQKV/128, MM/128), 256, 0, stream>>>(Xb, Wqkv, biasq, qkvf, MM, NQKV, Hh);
  rope_split_kernel<<<(MM*48)/4, 256, 0, stream>>>(qkvf, cosb, sinb, qbuf, kbuf, vbuf);

  u16* Wo = Wqkv;  // Wqkv dead after gemm1
  cast(wo, Wo, (size_t)4096 * 4096);

  u16* attn = Xb;  // Xb dead after gemm1
  flash_kernel<<<Bb*NKVv, 512, 0, stream>>>(qbuf, kbuf, vbuf, kc, vc, clens, attn);

  gemm_bt_kernel<<<dim3(Hh/128, MM/128), 256, 0, stream>>>(attn, Wo, nullptr, out, MM, Hh, Hh);
}

// Round 2
// 517.291 us; speedup vs baseline: 1.3481x; 1.3481x over previous
//
#include <hip/hip_runtime.h>
#include <stdint.h>
#include <stddef.h>

#define Bb 16
#define Ss 64
#define Hh 4096
#define NKVv 8
#define HDd 128
#define LCACHE 4608
#define MM (Bb*Ss)            // 1024
#define NQKV (Hh + 2*NKVv*HDd) // 6144
#define SCALE_Q 0.08838834764831845f
#define SPLITS 4

typedef float fx4 __attribute__((ext_vector_type(4)));
typedef short s16x8 __attribute__((ext_vector_type(8)));
typedef unsigned short u16;
typedef unsigned short u16x8 __attribute__((ext_vector_type(8)));
typedef unsigned short u16x4 __attribute__((ext_vector_type(4)));

__device__ __forceinline__ u16 f2bf(float f) {
  union { float f; unsigned u; } x; x.f = f;
  unsigned r = x.u + 0x7FFFu + ((x.u >> 16) & 1u);
  return (u16)(r >> 16);
}

__device__ __forceinline__ fx4 MFMA(s16x8 a, s16x8 b, fx4 c) {
  return __builtin_amdgcn_mfma_f32_16x16x32_bf16(a, b, c, 0, 0, 0);
}

// ---------------- cast f32 -> bf16 (8 elems/thread) ----------------
__global__ __launch_bounds__(256) void cast_bf16_kernel(
    const float* __restrict__ src, u16* __restrict__ dst, int n8) {
  int i = blockIdx.x * 256 + threadIdx.x;
  if (i >= n8) return;
  fx4 a = *(const fx4*)(src + (size_t)i * 8);
  fx4 b = *(const fx4*)(src + (size_t)i * 8 + 4);
  u16x8 o;
  o[0]=f2bf(a[0]); o[1]=f2bf(a[1]); o[2]=f2bf(a[2]); o[3]=f2bf(a[3]);
  o[4]=f2bf(b[0]); o[5]=f2bf(b[1]); o[6]=f2bf(b[2]); o[7]=f2bf(b[3]);
  *(u16x8*)(dst + (size_t)i * 8) = o;
}

// ---------------- BT-GEMM: C[m,n] = sum_k A[m,k]*W[n,k] + bias[n] ----------------
__global__ __launch_bounds__(256) void gemm_bt_kernel(
    const u16* __restrict__ A, const u16* __restrict__ W,
    const float* __restrict__ bias, float* __restrict__ C,
    int M, int N, int K)
{
  __shared__ __align__(16) u16 As[128*32];
  __shared__ __align__(16) u16 Ws[128*32];
  const int t = threadIdx.x;
  const int lane = t & 63, w = t >> 6;
  const int wr = (w >> 1) * 64, wc = (w & 1) * 64;
  const int lr = lane & 15, lg = lane >> 4;
  const int mt = blockIdx.y * 128, nt = blockIdx.x * 128;

  fx4 acc[4][4];
#pragma unroll
  for (int i = 0; i < 4; i++)
#pragma unroll
    for (int j = 0; j < 4; j++) acc[i][j] = (fx4){0.f,0.f,0.f,0.f};

  const int srow = t >> 2, scol = (t & 3) * 8;
  const u16* Ag0 = A + (size_t)(mt + srow) * K + scol;
  const u16* Ag1 = A + (size_t)(mt + 64 + srow) * K + scol;
  const u16* Wg0 = W + (size_t)(nt + srow) * K + scol;
  const u16* Wg1 = W + (size_t)(nt + 64 + srow) * K + scol;
  u16* As0 = As + srow*32 + scol;
  u16* As1 = As + (64+srow)*32 + scol;
  u16* Ws0 = Ws + srow*32 + scol;
  u16* Ws1 = Ws + (64+srow)*32 + scol;

  for (int k0 = 0; k0 < K; k0 += 32) {
    __syncthreads();
    *(u16x8*)As0 = *(const u16x8*)(Ag0 + k0);
    *(u16x8*)As1 = *(const u16x8*)(Ag1 + k0);
    *(u16x8*)Ws0 = *(const u16x8*)(Wg0 + k0);
    *(u16x8*)Ws1 = *(const u16x8*)(Wg1 + k0);
    __syncthreads();
    s16x8 af[4], bfr[4];
#pragma unroll
    for (int i = 0; i < 4; i++)
      af[i] = *(const s16x8*)(As + (wr + i*16 + lr)*32 + lg*8);
#pragma unroll
    for (int j = 0; j < 4; j++)
      bfr[j] = *(const s16x8*)(Ws + (wc + j*16 + lr)*32 + lg*8);
#pragma unroll
    for (int i = 0; i < 4; i++)
#pragma unroll
      for (int j = 0; j < 4; j++)
        acc[i][j] = MFMA(af[i], bfr[j], acc[i][j]);
  }

#pragma unroll
  for (int j = 0; j < 4; j++) {
    const int col = nt + wc + j*16 + lr;
    const float bv = bias ? bias[col] : 0.0f;
#pragma unroll
    for (int i = 0; i < 4; i++) {
      const int row0 = mt + wr + i*16 + lg*4;
#pragma unroll
      for (int q = 0; q < 4; q++)
        C[(size_t)(row0 + q) * N + col] = acc[i][j][q] + bv;
    }
  }
}

// ---------------- RoPE + repack to bf16 ----------------
__global__ __launch_bounds__(256) void rope_split_kernel(
    const float* __restrict__ qkv, const float* __restrict__ cosb,
    const float* __restrict__ sinb, u16* __restrict__ qb,
    u16* __restrict__ kb, u16* __restrict__ vb)
{
  const int wt = blockIdx.x * 4 + (threadIdx.x >> 6);
  const int lane = threadIdx.x & 63;
  const int m = wt / 48;
  const int task = wt - m * 48;
  const int b = m >> 6, s = m & 63;
  const float* row = qkv + (size_t)m * NQKV;

  if (task < 32) {
    const int h = task;
    const float x1 = row[h*128 + lane];
    const float x2 = row[h*128 + 64 + lane];
    const float c = cosb[m*128 + lane];
    const float sn = sinb[m*128 + lane];
    u16* dst = qb + (((size_t)(b*8 + (h>>2)))*256 + (h&3)*64 + s) * 128;
    dst[lane]      = f2bf((x1*c - x2*sn) * SCALE_Q);
    dst[lane + 64] = f2bf((x2*c + x1*sn) * SCALE_Q);
  } else if (task < 40) {
    const int n = task - 32;
    const float x1 = row[4096 + n*128 + lane];
    const float x2 = row[4096 + n*128 + 64 + lane];
    const float c = cosb[m*128 + lane];
    const float sn = sinb[m*128 + lane];
    u16* dst = kb + (((size_t)(b*8 + n))*64 + s) * 128;
    dst[lane]      = f2bf(x1*c - x2*sn);
    dst[lane + 64] = f2bf(x2*c + x1*sn);
  } else {
    const int n = task - 40;
    const float x1 = row[5120 + n*128 + lane];
    const float x2 = row[5120 + n*128 + 64 + lane];
    u16* dst = vb + (((size_t)(b*8 + n))*64 + s) * 128;
    dst[lane]      = f2bf(x1);
    dst[lane + 64] = f2bf(x2);
  }
}

// ---------------- fused flash attention, KV-split ----------------
// block = (b, kv-head n, split). 512 threads = 8 waves, each wave owns 32 query
// rows. Split s handles cache tiles [s*chunk, min((s+1)*chunk, ntile)); split 3
// additionally handles the causal "current" tile. Writes unnormalized partials.
__global__ __launch_bounds__(512) void flash_kernel(
    const u16* __restrict__ qb, const u16* __restrict__ kb, const u16* __restrict__ vb,
    const float* __restrict__ kc, const float* __restrict__ vc,
    const int* __restrict__ cache_lens,
    float* __restrict__ Op, float* __restrict__ mlp)
{
  __shared__ __align__(16) u16 Kt[64*128];   // [t][d], byte ^ ((t&7)<<4)
  __shared__ __align__(16) u16 Vt[128*64];   // [d][t], byte ^ ((d&7)<<4)
  __shared__ __align__(16) u16 Pl[8*32*64];  // per-wave P, byte ^ (((row>>2)&3)<<5)

  const int bid = blockIdx.x;
  const int split = bid & (SPLITS-1);
  const int bn = bid >> 2;
  const int b = bn >> 3, n = bn & 7;
  const int t = threadIdx.x;
  const int lane = t & 63, w = t >> 6;
  const int lr = lane & 15, lg = lane >> 4;
  const int L = cache_lens[b];

  s16x8 qf[2][4];
  const u16* qbase = qb + ((size_t)bn*256 + w*32) * 128;
#pragma unroll
  for (int rf = 0; rf < 2; rf++)
#pragma unroll
    for (int ks = 0; ks < 4; ks++)
      qf[rf][ks] = *(const s16x8*)(qbase + (rf*16 + lr)*128 + ks*32 + lg*8);

  fx4 O[2][8];
  float m_r[2][4], l_r[2][4];
#pragma unroll
  for (int rf = 0; rf < 2; rf++) {
#pragma unroll
    for (int cn = 0; cn < 8; cn++) O[rf][cn] = (fx4){0.f,0.f,0.f,0.f};
#pragma unroll
    for (int i = 0; i < 4; i++) { m_r[rf][i] = -1e30f; l_r[rf][i] = 0.f; }
  }

  const int ntile = (L + 63) >> 6;
  const int chunk = (ntile + SPLITS - 1) / SPLITS;
  const int t0 = split * chunk;
  const int t1 = min(t0 + chunk, ntile);
  const int tend = (split == SPLITS-1) ? t1 + 1 : t1;

  const int krow = t >> 3, kcol = (t & 7) * 16;
  const int vd0 = (t >> 4) * 4, vr0 = (t & 15) * 4;
  char* pw = (char*)Pl + w * 4096;

  for (int tile = t0; tile < tend; ++tile) {
    const int l0 = tile * 64;
    const bool cur = (split == SPLITS-1) && (tile == t1);
    __syncthreads();
    if (!cur) {
      { // K tile f32 -> bf16, row-major [t][d]
        const float* src = kc + (((size_t)b*LCACHE + l0 + krow)*NKVv + n)*HDd + kcol;
        const bool valid = (l0 + krow) < L;
#pragma unroll
        for (int jj = 0; jj < 2; jj++) {
          u16x8 v8 = {0,0,0,0,0,0,0,0};
          if (valid) {
            fx4 f0 = *(const fx4*)(src + jj*8);
            fx4 f1 = *(const fx4*)(src + jj*8 + 4);
            v8[0]=f2bf(f0[0]); v8[1]=f2bf(f0[1]); v8[2]=f2bf(f0[2]); v8[3]=f2bf(f0[3]);
            v8[4]=f2bf(f1[0]); v8[5]=f2bf(f1[1]); v8[6]=f2bf(f1[2]); v8[7]=f2bf(f1[3]);
          }
          const int byt = (krow*256 + (kcol + jj*8)*2) ^ ((krow & 7) << 4);
          *(u16x8*)((char*)Kt + byt) = v8;
        }
      }
      { // V tile transposed [d][t]
        const float* srcv = vc + (((size_t)b*LCACHE + l0 + vr0)*NKVv + n)*HDd + vd0;
        fx4 vv[4];
        const fx4 z = {0.f,0.f,0.f,0.f};
#pragma unroll
        for (int j = 0; j < 4; j++) {
          const bool valid = (l0 + vr0 + j) < L;
          vv[j] = valid ? *(const fx4*)(srcv + (size_t)j*(NKVv*HDd)) : z;
        }
#pragma unroll
        for (int dd = 0; dd < 4; dd++) {
          u16x4 pk;
          pk[0]=f2bf(vv[0][dd]); pk[1]=f2bf(vv[1][dd]); pk[2]=f2bf(vv[2][dd]); pk[3]=f2bf(vv[3][dd]);
          const int d = vd0 + dd;
          const int byt = (d*128 + vr0*2) ^ ((d & 7) << 4);
          *(u16x4*)((char*)Vt + byt) = pk;
        }
      }
    } else {
      { // current K tile from kb (bf16 already)
        const u16* src = kb + ((size_t)bn*64 + krow)*128 + kcol;
#pragma unroll
        for (int jj = 0; jj < 2; jj++) {
          u16x8 v8 = *(const u16x8*)(src + jj*8);
          const int byt = (krow*256 + (kcol + jj*8)*2) ^ ((krow & 7) << 4);
          *(u16x8*)((char*)Kt + byt) = v8;
        }
      }
      { // current V tile transposed
        const u16* srcv = vb + (size_t)bn*64*128 + (size_t)vr0*128 + vd0;
        u16x4 vv[4];
#pragma unroll
        for (int j = 0; j < 4; j++) vv[j] = *(const u16x4*)(srcv + j*128);
#pragma unroll
        for (int dd = 0; dd < 4; dd++) {
          u16x4 pk; pk[0]=vv[0][dd]; pk[1]=vv[1][dd]; pk[2]=vv[2][dd]; pk[3]=vv[3][dd];
          const int d = vd0 + dd;
          const int byt = (d*128 + vr0*2) ^ ((d & 7) << 4);
          *(u16x4*)((char*)Vt + byt) = pk;
        }
      }
    }
    __syncthreads();

    // QK^T
    fx4 sc[2][4];
#pragma unroll
    for (int cf = 0; cf < 4; cf++) {
      s16x8 kf[4];
      const int trow = cf*16 + lr;
#pragma unroll
      for (int ks = 0; ks < 4; ks++) {
        const int byt = (trow*256 + (ks*32 + lg*8)*2) ^ ((trow & 7) << 4);
        kf[ks] = *(const s16x8*)((char*)Kt + byt);
      }
#pragma unroll
      for (int rf = 0; rf < 2; rf++) {
        fx4 s = {0.f,0.f,0.f,0.f};
#pragma unroll
        for (int ks = 0; ks < 4; ks++) s = MFMA(qf[rf][ks], kf[ks], s);
        sc[rf][cf] = s;
      }
    }

    // masking
    if (cur) {
#pragma unroll
      for (int rf = 0; rf < 2; rf++)
#pragma unroll
        for (int cf = 0; cf < 4; cf++) {
          const int col = cf*16 + lr;
#pragma unroll
          for (int i = 0; i < 4; i++) {
            const int sq = (w & 1)*32 + rf*16 + lg*4 + i;
            if (col > sq) sc[rf][cf][i] = -1e30f;
          }
        }
    } else if (l0 + 64 > L) {
#pragma unroll
      for (int cf = 0; cf < 4; cf++) {
        const int tp = l0 + cf*16 + lr;
        if (tp >= L) {
#pragma unroll
          for (int rf = 0; rf < 2; rf++)
#pragma unroll
            for (int i = 0; i < 4; i++) sc[rf][cf][i] = -1e30f;
        }
      }
    }

    // online softmax + write P (bf16) to per-wave LDS
#pragma unroll
    for (int rf = 0; rf < 2; rf++) {
#pragma unroll
      for (int i = 0; i < 4; i++) {
        float v = fmaxf(fmaxf(sc[rf][0][i], sc[rf][1][i]), fmaxf(sc[rf][2][i], sc[rf][3][i]));
        v = fmaxf(v, __shfl_xor(v, 1));
        v = fmaxf(v, __shfl_xor(v, 2));
        v = fmaxf(v, __shfl_xor(v, 4));
        v = fmaxf(v, __shfl_xor(v, 8));
        const float nm = fmaxf(m_r[rf][i], v);
        const float sf = __expf(m_r[rf][i] - nm);
        m_r[rf][i] = nm;
        float rs = 0.f;
#pragma unroll
        for (int cf = 0; cf < 4; cf++) {
          const float p = __expf(sc[rf][cf][i] - nm);
          sc[rf][cf][i] = p;
          rs += p;
        }
        rs += __shfl_xor(rs, 1);
        rs += __shfl_xor(rs, 2);
        rs += __shfl_xor(rs, 4);
        rs += __shfl_xor(rs, 8);
        l_r[rf][i] = l_r[rf][i]*sf + rs;
#pragma unroll
        for (int cn = 0; cn < 8; cn++) O[rf][cn][i] *= sf;
      }
#pragma unroll
      for (int cf = 0; cf < 4; cf++)
#pragma unroll
        for (int i = 0; i < 4; i++) {
          const int prow = rf*16 + lg*4 + i;
          const int pcol = cf*16 + lr;
          const int byt = (prow*128 + pcol*2) ^ (((prow >> 2) & 3) << 5);
          *(u16*)(pw + byt) = f2bf(sc[rf][cf][i]);
        }
    }

    // PV: O += P @ V
#pragma unroll
    for (int ks = 0; ks < 2; ks++) {
      s16x8 vf[8];
#pragma unroll
      for (int cn = 0; cn < 8; cn++) {
        const int c = cn*16 + lr;
        const int byt = (c*128 + (ks*32 + lg*8)*2) ^ ((c & 7) << 4);
        vf[cn] = *(const s16x8*)((char*)Vt + byt);
      }
#pragma unroll
      for (int rf = 0; rf < 2; rf++) {
        const int prow = rf*16 + lr;
        const int byt = (prow*128 + (ks*32 + lg*8)*2) ^ (((prow >> 2) & 3) << 5);
        const s16x8 pf = *(const s16x8*)(pw + byt);
#pragma unroll
        for (int cn = 0; cn < 8; cn++)
          O[rf][cn] = MFMA(pf, vf[cn], O[rf][cn]);
      }
    }
  }

  // write unnormalized partials: Op[(bn*SPLITS+split)][prow][128], ml pairs
  const size_t pbase = ((size_t)(bn*SPLITS + split)) * 256;
#pragma unroll
  for (int rf = 0; rf < 2; rf++)
#pragma unroll
    for (int i = 0; i < 4; i++) {
      const int prow = (w >> 1)*64 + (w & 1)*32 + rf*16 + lg*4 + i;
      float* dst = Op + (pbase + prow)*128;
#pragma unroll
      for (int cn = 0; cn < 8; cn++)
        dst[cn*16 + lr] = O[rf][cn][i];
      if (lr == 0) {
        mlp[(pbase + prow)*2]     = m_r[rf][i];
        mlp[(pbase + prow)*2 + 1] = l_r[rf][i];
      }
    }
}

// ---------------- LSE merge of the 4 splits -> bf16 attn [1024][4096] ----------------
__global__ __launch_bounds__(256) void merge_kernel(
    const float* __restrict__ Op, const float* __restrict__ mlp,
    u16* __restrict__ attn)
{
  const int gid = blockIdx.x * 4 + (threadIdx.x >> 6);  // row id in [0, 128*256)
  const int lane = threadIdx.x & 63;
  const int bn = gid >> 8, prow = gid & 255;
  const int b = bn >> 3, n = bn & 7;
  const int g = prow >> 6, srow = prow & 63;

  float mi[SPLITS], li[SPLITS];
  float M = -1e30f;
#pragma unroll
  for (int s = 0; s < SPLITS; s++) {
    const size_t base = ((size_t)(bn*SPLITS + s))*256 + prow;
    mi[s] = mlp[base*2];
    li[s] = mlp[base*2 + 1];
    M = fmaxf(M, mi[s]);
  }
  float ltot = 0.f, sc[SPLITS];
#pragma unroll
  for (int s = 0; s < SPLITS; s++) {
    sc[s] = __expf(mi[s] - M);
    ltot += sc[s] * li[s];
  }
  const float inv = 1.f / ltot;

  float ox = 0.f, oy = 0.f;
#pragma unroll
  for (int s = 0; s < SPLITS; s++) {
    const float* src = Op + (((size_t)(bn*SPLITS + s))*256 + prow)*128 + lane*2;
    ox += sc[s] * src[0];
    oy += sc[s] * src[1];
  }
  u16* dst = attn + ((size_t)(b*64 + srow))*4096 + (size_t)(n*4 + g)*128 + lane*2;
  dst[0] = f2bf(ox * inv);
  dst[1] = f2bf(oy * inv);
}

// ---------------- launch ----------------
extern "C" void kernel_launch(void* const* d_in, const int* in_sizes, int n_in,
                              void* d_out, int out_size, void* d_ws, size_t ws_size,
                              hipStream_t stream) {
  (void)in_sizes; (void)n_in; (void)out_size; (void)ws_size;
  const float* hidden = (const float*)d_in[0];
  const float* cosb   = (const float*)d_in[1];
  const float* sinb   = (const float*)d_in[2];
  const float* kc     = (const float*)d_in[3];
  const float* vc     = (const float*)d_in[4];
  const float* wq     = (const float*)d_in[5];
  const float* bq     = (const float*)d_in[6];
  const float* wk     = (const float*)d_in[7];
  const float* bk     = (const float*)d_in[8];
  const float* wv     = (const float*)d_in[9];
  const float* bv     = (const float*)d_in[10];
  const float* wo     = (const float*)d_in[11];
  const int* clens    = (const int*)d_in[12];
  float* out = (float*)d_out;

  char* ws = (char*)d_ws;
  size_t off = 0;
  auto alloc = [&](size_t bytes) -> void* {
    void* p = ws + off; off += (bytes + 255) & ~(size_t)255; return p;
  };
  u16* Wqkv  = (u16*)alloc((size_t)NQKV * Hh * 2);          // 50.3 MB (reused for wo)
  u16* Xb    = (u16*)alloc((size_t)MM * Hh * 2);            // 8 MB (reused for attn)
  float* qkvf= (float*)alloc((size_t)MM * NQKV * 4);        // 24 MB
  u16* qbuf  = (u16*)alloc((size_t)Bb*NKVv*256*HDd*2);      // 8 MB
  u16* kbuf  = (u16*)alloc((size_t)Bb*NKVv*64*HDd*2);       // 2 MB
  u16* vbuf  = (u16*)alloc((size_t)Bb*NKVv*64*HDd*2);       // 2 MB
  float* biasq = (float*)alloc((size_t)NQKV * 4);
  float* Op  = (float*)alloc((size_t)Bb*NKVv*SPLITS*256*128*4); // 67.1 MB
  float* mlp = (float*)alloc((size_t)Bb*NKVv*SPLITS*256*2*4);   // 1 MB

  hipMemcpyAsync(biasq,        bq, 4096*sizeof(float), hipMemcpyDeviceToDevice, stream);
  hipMemcpyAsync(biasq + 4096, bk, 1024*sizeof(float), hipMemcpyDeviceToDevice, stream);
  hipMemcpyAsync(biasq + 5120, bv, 1024*sizeof(float), hipMemcpyDeviceToDevice, stream);

  auto cast = [&](const float* s, u16* d, size_t nelem) {
    int n8 = (int)(nelem / 8);
    cast_bf16_kernel<<<(n8 + 255) / 256, 256, 0, stream>>>(s, d, n8);
  };
  cast(hidden, Xb, (size_t)MM * Hh);
  cast(wq, Wqkv,                      (size_t)4096 * 4096);
  cast(wk, Wqkv + (size_t)4096*4096,  (size_t)1024 * 4096);
  cast(wv, Wqkv + (size_t)5120*4096,  (size_t)1024 * 4096);

  gemm_bt_kernel<<<dim3(NQKV/128, MM/128), 256, 0, stream>>>(Xb, Wqkv, biasq, qkvf, MM, NQKV, Hh);
  rope_split_kernel<<<(MM*48)/4, 256, 0, stream>>>(qkvf, cosb, sinb, qbuf, kbuf, vbuf);

  u16* Wo = Wqkv;  // Wqkv dead after gemm1
  cast(wo, Wo, (size_t)4096 * 4096);

  flash_kernel<<<Bb*NKVv*SPLITS, 512, 0, stream>>>(qbuf, kbuf, vbuf, kc, vc, clens, Op, mlp);

  u16* attn = Xb;  // Xb dead after gemm1
  merge_kernel<<<(Bb*NKVv*256)/4, 256, 0, stream>>>(Op, mlp, attn);

  gemm_bt_kernel<<<dim3(Hh/128, MM/128), 256, 0, stream>>>(attn, Wo, nullptr, out, MM, Hh, Hh);
}